// Round 1
// baseline (361.941 us; speedup 1.0000x reference)
//
#include <hip/hip_runtime.h>

typedef long long ll;

#define PPI   65536      // pixels per image (256*256)
#define NPIX  524288     // total pixels (8 images)
#define NCH   64         // feat channels
#define NB    16         // bottleneck channels
#define NC    64         // num_colors
#define BN_EPS 1e-5

// ---------------------------------------------------------------------------
// Kernel 1: bottleneck conv -> accumulate per-channel sum / sumsq of x
// ---------------------------------------------------------------------------
__global__ __launch_bounds__(256) void k_stats(const float* __restrict__ feat,
                                               const float* __restrict__ wb,
                                               const float* __restrict__ bb,
                                               double* __restrict__ gsum,
                                               double* __restrict__ gsq)
{
    const int P = 4;                       // pixels per thread
    int tid = threadIdx.x;
    int b   = blockIdx.x >> 6;             // 64 blocks per image (1024 px/block)
    int p0  = (blockIdx.x & 63) * 1024 + tid;
    const float* fb = feat + (ll)b * NCH * PPI + p0;

    float acc[NB][P];
#pragma unroll
    for (int o = 0; o < NB; ++o)
#pragma unroll
        for (int j = 0; j < P; ++j) acc[o][j] = 0.f;

#pragma unroll 4
    for (int c = 0; c < NCH; ++c) {
        float f[P];
#pragma unroll
        for (int j = 0; j < P; ++j) f[j] = fb[(ll)c * PPI + j * 256];
#pragma unroll
        for (int o = 0; o < NB; ++o) {
            float wv = wb[o * NCH + c];    // wave-uniform -> s_load
#pragma unroll
            for (int j = 0; j < P; ++j) acc[o][j] = fmaf(f[j], wv, acc[o][j]);
        }
    }

    __shared__ float wsum[4][NB];
    __shared__ float wsq[4][NB];
    int wave = tid >> 6, lane = tid & 63;
#pragma unroll
    for (int o = 0; o < NB; ++o) {
        float bo = bb[o];
        float s = 0.f, q = 0.f;
#pragma unroll
        for (int j = 0; j < P; ++j) { float x = acc[o][j] + bo; s += x; q = fmaf(x, x, q); }
        for (int off = 32; off > 0; off >>= 1) {
            s += __shfl_down(s, off);
            q += __shfl_down(q, off);
        }
        if (lane == 0) { wsum[wave][o] = s; wsq[wave][o] = q; }
    }
    __syncthreads();
    if (tid < NB) {
        double s = (double)wsum[0][tid] + wsum[1][tid] + wsum[2][tid] + wsum[3][tid];
        double q = (double)wsq[0][tid] + wsq[1][tid] + wsq[2][tid] + wsq[3][tid];
        atomicAdd(&gsum[tid], s);
        atomicAdd(&gsq[tid], q);
    }
}

// ---------------------------------------------------------------------------
// Kernel 2: finalize BN scale/shift; fold w_mask group-mean into w_eff[64][16]
// ---------------------------------------------------------------------------
__global__ void k_finalize(const double* __restrict__ gsum,
                           const double* __restrict__ gsq,
                           const float* __restrict__ gamma,
                           const float* __restrict__ beta,
                           const float* __restrict__ wm,
                           float* __restrict__ scl,
                           float* __restrict__ shf,
                           float* __restrict__ weff)
{
    int t = threadIdx.x;                   // 64 threads
    if (t < NB) {
        double mu  = gsum[t] / (double)NPIX;
        double var = gsq[t] / (double)NPIX - mu * mu;
        double sc  = (double)gamma[t] / sqrt(var + BN_EPS);
        scl[t] = (float)sc;
        shf[t] = (float)((double)beta[t] - mu * sc);
    }
    if (t < NC) {
#pragma unroll
        for (int o = 0; o < NB; ++o) {
            float v = 0.25f * (wm[(0 * 64 + t) * NB + o] + wm[(1 * 64 + t) * NB + o] +
                               wm[(2 * 64 + t) * NB + o] + wm[(3 * 64 + t) * NB + o]);
            weff[t * NB + o] = v;
        }
    }
}

// ---------------------------------------------------------------------------
// Kernel 3: recompute x -> BN+ReLU -> 64 logits -> top4+softmax -> dense m,
//           per-pixel records, palette numerator/denominator accumulation
// ---------------------------------------------------------------------------
__global__ __launch_bounds__(256) void k_main(const float* __restrict__ feat,
                                              const float* __restrict__ img,
                                              const float* __restrict__ wb,
                                              const float* __restrict__ bb,
                                              const float* __restrict__ scl,
                                              const float* __restrict__ shf,
                                              const float* __restrict__ weff,
                                              float* __restrict__ m_out,
                                              unsigned* __restrict__ idx_out,
                                              float* __restrict__ sm_out,
                                              float* __restrict__ den_g,
                                              float* __restrict__ num_g)
{
    const int P = 2;                       // pixels per thread
    __shared__ float den_loc[NC];
    __shared__ float num_loc[3 * NC];
    int tid = threadIdx.x;
    if (tid < NC) den_loc[tid] = 0.f;
    if (tid < 3 * NC) num_loc[tid] = 0.f;
    __syncthreads();

    int b  = blockIdx.x >> 7;              // 128 blocks per image (512 px/block)
    int p0 = (blockIdx.x & 127) * 512 + tid;
    const float* fb = feat + (ll)b * NCH * PPI + p0;

    float acc[NB][P];
#pragma unroll
    for (int o = 0; o < NB; ++o)
#pragma unroll
        for (int j = 0; j < P; ++j) acc[o][j] = 0.f;

#pragma unroll 4
    for (int c = 0; c < NCH; ++c) {
        float f[P];
#pragma unroll
        for (int j = 0; j < P; ++j) f[j] = fb[(ll)c * PPI + j * 256];
#pragma unroll
        for (int o = 0; o < NB; ++o) {
            float wv = wb[o * NCH + c];
#pragma unroll
            for (int j = 0; j < P; ++j) acc[o][j] = fmaf(f[j], wv, acc[o][j]);
        }
    }

    // BN + ReLU (bias folded into shift)
#pragma unroll
    for (int o = 0; o < NB; ++o) {
        float sc = scl[o];
        float sh = fmaf(bb[o], sc, shf[o]);
#pragma unroll
        for (int j = 0; j < P; ++j) acc[o][j] = fmaxf(0.f, fmaf(acc[o][j], sc, sh));
    }

    // logits over 64 colors + streaming top-4 (strict > replicates jax tie-break)
    float tv[P][4];
    int   ti[P][4];
#pragma unroll
    for (int j = 0; j < P; ++j)
#pragma unroll
        for (int k = 0; k < 4; ++k) { tv[j][k] = -3.4e38f; ti[j][k] = 0; }

    for (int n = 0; n < NC; ++n) {
        float v[P];
#pragma unroll
        for (int j = 0; j < P; ++j) v[j] = 0.f;
#pragma unroll
        for (int o = 0; o < NB; ++o) {
            float wv = weff[n * NB + o];
#pragma unroll
            for (int j = 0; j < P; ++j) v[j] = fmaf(acc[o][j], wv, v[j]);
        }
#pragma unroll
        for (int j = 0; j < P; ++j) {
            float vv = v[j];
            if (vv > tv[j][3]) {
                if (vv > tv[j][0]) {
                    tv[j][3] = tv[j][2]; ti[j][3] = ti[j][2];
                    tv[j][2] = tv[j][1]; ti[j][2] = ti[j][1];
                    tv[j][1] = tv[j][0]; ti[j][1] = ti[j][0];
                    tv[j][0] = vv;       ti[j][0] = n;
                } else if (vv > tv[j][1]) {
                    tv[j][3] = tv[j][2]; ti[j][3] = ti[j][2];
                    tv[j][2] = tv[j][1]; ti[j][2] = ti[j][1];
                    tv[j][1] = vv;       ti[j][1] = n;
                } else if (vv > tv[j][2]) {
                    tv[j][3] = tv[j][2]; ti[j][3] = ti[j][2];
                    tv[j][2] = vv;       ti[j][2] = n;
                } else {
                    tv[j][3] = vv;       ti[j][3] = n;
                }
            }
        }
    }

    // softmax over the 4 kept values
    float sm[P][4];
#pragma unroll
    for (int j = 0; j < P; ++j) {
        float m0 = tv[j][0];
        float e0 = 1.0f;
        float e1 = expf(tv[j][1] - m0);
        float e2 = expf(tv[j][2] - m0);
        float e3 = expf(tv[j][3] - m0);
        float Z  = e0 + e1 + e2 + e3;
        sm[j][0] = e0 / Z; sm[j][1] = e1 / Z; sm[j][2] = e2 / Z; sm[j][3] = e3 / Z;
    }

    // dense m write (select-or-zero) — replaces memset+scatter
#pragma unroll 1
    for (int n = 0; n < NC; ++n) {
#pragma unroll
        for (int j = 0; j < P; ++j) {
            float val = 0.f;
            val = (n == ti[j][0]) ? sm[j][0] : val;
            val = (n == ti[j][1]) ? sm[j][1] : val;
            val = (n == ti[j][2]) ? sm[j][2] : val;
            val = (n == ti[j][3]) ? sm[j][3] : val;
            m_out[((ll)b * NC + n) * PPI + p0 + j * 256] = val;
        }
    }

    // per-pixel records + palette accumulation
#pragma unroll
    for (int j = 0; j < P; ++j) {
        int p = p0 + j * 256;
        ll gp = (ll)b * PPI + p;
        idx_out[gp] = (unsigned)ti[j][0] | ((unsigned)ti[j][1] << 8) |
                      ((unsigned)ti[j][2] << 16) | ((unsigned)ti[j][3] << 24);
        sm_out[gp]             = sm[j][0];
        sm_out[(ll)NPIX + gp]  = sm[j][1];
        sm_out[2ll * NPIX + gp] = sm[j][2];
        sm_out[3ll * NPIX + gp] = sm[j][3];
        float i0 = img[((ll)b * 3 + 0) * PPI + p];
        float i1 = img[((ll)b * 3 + 1) * PPI + p];
        float i2 = img[((ll)b * 3 + 2) * PPI + p];
#pragma unroll
        for (int k = 0; k < 4; ++k) {
            float s = sm[j][k];
            int   n = ti[j][k];
            atomicAdd(&den_loc[n], s);
            atomicAdd(&num_loc[n], s * i0);
            atomicAdd(&num_loc[NC + n], s * i1);
            atomicAdd(&num_loc[2 * NC + n], s * i2);
        }
    }
    __syncthreads();
    if (tid < NC)     atomicAdd(&den_g[b * NC + tid], den_loc[tid]);
    if (tid < 3 * NC) atomicAdd(&num_g[(ll)b * 3 * NC + tid], num_loc[tid]);
}

// ---------------------------------------------------------------------------
// Kernel 4: palette = num / (den + 1e-8)
// ---------------------------------------------------------------------------
__global__ void k_palette(const float* __restrict__ den_g,
                          const float* __restrict__ num_g,
                          float* __restrict__ pal_out)
{
    int t = blockIdx.x * blockDim.x + threadIdx.x;  // 0..511
    if (t >= 8 * NC) return;
    int b = t >> 6, n = t & 63;
    float d = den_g[t] + 1e-8f;
#pragma unroll
    for (int c = 0; c < 3; ++c)
        pal_out[((ll)b * 3 + c) * NC + n] = num_g[((ll)b * 3 + c) * NC + n] / d;
}

// ---------------------------------------------------------------------------
// Kernel 5: transformed_img[c] = sum_k sm_k * pal[c][idx_k]
// ---------------------------------------------------------------------------
__global__ __launch_bounds__(256) void k_recon(const unsigned* __restrict__ idx_in,
                                               const float* __restrict__ sm_in,
                                               const float* __restrict__ pal,
                                               float* __restrict__ tout)
{
    const int P = 4;
    __shared__ float lpal[3 * NC];
    int tid = threadIdx.x;
    int b   = blockIdx.x >> 6;             // 64 blocks per image (1024 px/block)
    int p0  = (blockIdx.x & 63) * 1024 + tid;
    if (tid < 3 * NC) lpal[tid] = pal[(ll)b * 3 * NC + tid];
    __syncthreads();

#pragma unroll
    for (int j = 0; j < P; ++j) {
        int p = p0 + j * 256;
        ll gp = (ll)b * PPI + p;
        unsigned pk = idx_in[gp];
        int t0 = pk & 255, t1 = (pk >> 8) & 255, t2 = (pk >> 16) & 255, t3 = pk >> 24;
        float s0 = sm_in[gp];
        float s1 = sm_in[(ll)NPIX + gp];
        float s2 = sm_in[2ll * NPIX + gp];
        float s3 = sm_in[3ll * NPIX + gp];
#pragma unroll
        for (int c = 0; c < 3; ++c) {
            float v = s0 * lpal[c * NC + t0] + s1 * lpal[c * NC + t1] +
                      s2 * lpal[c * NC + t2] + s3 * lpal[c * NC + t3];
            tout[((ll)b * 3 + c) * PPI + p] = v;
        }
    }
}

// ---------------------------------------------------------------------------
extern "C" void kernel_launch(void* const* d_in, const int* in_sizes, int n_in,
                              void* d_out, int out_size, void* d_ws, size_t ws_size,
                              hipStream_t stream)
{
    const float* img   = (const float*)d_in[0];
    const float* feat  = (const float*)d_in[1];
    const float* wb    = (const float*)d_in[2];
    const float* bb    = (const float*)d_in[3];
    const float* gamma = (const float*)d_in[4];
    const float* beta  = (const float*)d_in[5];
    const float* wm    = (const float*)d_in[6];

    char* ws = (char*)d_ws;
    double*   gsum  = (double*)(ws + 0);          // 16 doubles
    double*   gsq   = (double*)(ws + 128);        // 16 doubles
    float*    den_g = (float*)(ws + 256);         // 8*64
    float*    num_g = (float*)(ws + 2304);        // 8*3*64
    float*    weff  = (float*)(ws + 8448);        // 64*16
    float*    scl   = (float*)(ws + 12544);       // 16
    float*    shf   = (float*)(ws + 12608);       // 16
    unsigned* idx4  = (unsigned*)(ws + 12672);    // NPIX
    float*    smarr = (float*)(ws + 12672 + 4ll * NPIX); // 4*NPIX

    float* t_out   = (float*)d_out;               // [8,3,256,256]
    float* m_out   = t_out + 3ll * NPIX;          // [8,64,256,256]
    float* pal_out = m_out + 64ll * NPIX;         // [8,3,64,1,1]

    // zero the atomic accumulators (ws is poisoned 0xAA before every launch)
    hipMemsetAsync(ws, 0, 8448, stream);

    k_stats<<<NPIX / 1024, 256, 0, stream>>>(feat, wb, bb, gsum, gsq);
    k_finalize<<<1, 64, 0, stream>>>(gsum, gsq, gamma, beta, wm, scl, shf, weff);
    k_main<<<NPIX / 512, 256, 0, stream>>>(feat, img, wb, bb, scl, shf, weff,
                                           m_out, idx4, smarr, den_g, num_g);
    k_palette<<<2, 256, 0, stream>>>(den_g, num_g, pal_out);
    k_recon<<<NPIX / 1024, 256, 0, stream>>>(idx4, smarr, pal_out, t_out);
}

// Round 3
// 355.955 us; speedup vs baseline: 1.0168x; 1.0168x over previous
//
#include <hip/hip_runtime.h>

typedef long long ll;

#define PPI   65536      // pixels per image (256*256)
#define NPIX  524288     // total pixels (8 images)
#define NCH   64         // feat channels
#define NB    16         // bottleneck channels
#define NC    64         // num_colors
#define BN_EPS 1e-5

// ---------------------------------------------------------------------------
// k1: 1x1 conv (bias dropped — cancels under BN mean-subtraction), store x
//     into the m-output region (channels 48..63), accumulate BN sum/sumsq.
// ---------------------------------------------------------------------------
__global__ __launch_bounds__(256) void k_conv(const float* __restrict__ feat,
                                              const float* __restrict__ wb,
                                              double* __restrict__ gsum,
                                              double* __restrict__ gsq,
                                              float* __restrict__ xout)
{
    const int tid = threadIdx.x;
    const int wave = tid >> 6, lane = tid & 63;
    const int b   = blockIdx.x >> 6;                     // 64 blocks per image
    const int p0  = ((blockIdx.x & 63) << 10) + (tid << 2); // 4 contiguous px
    const float* fb = feat + (ll)b * NCH * PPI + p0;

    float4 acc[NB];
#pragma unroll
    for (int o = 0; o < NB; ++o) acc[o] = make_float4(0.f, 0.f, 0.f, 0.f);

#pragma unroll 4
    for (int c = 0; c < NCH; ++c) {
        float4 f = *reinterpret_cast<const float4*>(fb + (ll)c * PPI);
#pragma unroll
        for (int o = 0; o < NB; ++o) {
            float wv = wb[o * NCH + c];                  // wave-uniform -> s_load
            acc[o].x = fmaf(f.x, wv, acc[o].x);
            acc[o].y = fmaf(f.y, wv, acc[o].y);
            acc[o].z = fmaf(f.z, wv, acc[o].z);
            acc[o].w = fmaf(f.w, wv, acc[o].w);
        }
    }

    // stash x in m[b][48+o][p] (k2 consumes then overwrites)
#pragma unroll
    for (int o = 0; o < NB; ++o)
        *reinterpret_cast<float4*>(xout + ((ll)(b * NC + 48 + o)) * PPI + p0) = acc[o];

    // BN stats
    __shared__ float red_s[4][NB], red_q[4][NB];
#pragma unroll
    for (int o = 0; o < NB; ++o) {
        float s = (acc[o].x + acc[o].y) + (acc[o].z + acc[o].w);
        float q = fmaf(acc[o].x, acc[o].x, acc[o].y * acc[o].y) +
                  fmaf(acc[o].z, acc[o].z, acc[o].w * acc[o].w);
#pragma unroll
        for (int off = 32; off > 0; off >>= 1) {
            s += __shfl_down(s, off);
            q += __shfl_down(q, off);
        }
        if (lane == 0) { red_s[wave][o] = s; red_q[wave][o] = q; }
    }
    __syncthreads();
    if (tid < NB) {
        atomicAdd(&gsum[tid], (double)red_s[0][tid] + red_s[1][tid] + red_s[2][tid] + red_s[3][tid]);
        atomicAdd(&gsq[tid],  (double)red_q[0][tid] + red_q[1][tid] + red_q[2][tid] + red_q[3][tid]);
    }
}

// ---------------------------------------------------------------------------
// k2: BN+ReLU on x (read from m region), logits, top-4, softmax, dense m,
//     per-pixel records, palette num/den accumulation.
//     NOTE: m_out deliberately NOT __restrict__ — x lives inside it.
// ---------------------------------------------------------------------------
__global__ __launch_bounds__(256) void k_mask(const float* __restrict__ img,
                                              const float* __restrict__ gamma,
                                              const float* __restrict__ beta,
                                              const float* __restrict__ wm,
                                              const double* __restrict__ gsum,
                                              const double* __restrict__ gsq,
                                              float* __restrict__ den_g,
                                              float* __restrict__ num_g,
                                              float* m_out,
                                              unsigned* __restrict__ idx_out,
                                              float* __restrict__ sm_out)
{
    __shared__ float weff_l[NC][NB];
    __shared__ float den_loc[4][NC];
    __shared__ float num_loc[4][3 * NC];
    __shared__ float scl_l[NB], shf_l[NB];

    const int tid = threadIdx.x;
    const int wave = tid >> 6;
    const int b   = blockIdx.x >> 6;
    const int p0  = ((blockIdx.x & 63) << 10) + (tid << 2);

    for (int i = tid; i < NC * NB; i += 256) {
        int n = i >> 4, o = i & 15;
        weff_l[n][o] = 0.25f * (wm[n * NB + o] + wm[(64 + n) * NB + o] +
                                wm[(128 + n) * NB + o] + wm[(192 + n) * NB + o]);
    }
    for (int i = tid; i < 4 * NC; i += 256) den_loc[i >> 6][i & 63] = 0.f;
    for (int i = tid; i < 4 * 3 * NC; i += 256) num_loc[i / (3 * NC)][i % (3 * NC)] = 0.f;
    if (tid < NB) {
        double mu  = gsum[tid] * (1.0 / NPIX);
        double var = gsq[tid] * (1.0 / NPIX) - mu * mu;
        double sc  = (double)gamma[tid] / sqrt(var + BN_EPS);
        scl_l[tid] = (float)sc;
        shf_l[tid] = (float)((double)beta[tid] - mu * sc);
    }
    __syncthreads();

    // load x (registers), BN + ReLU
    float4 xx[NB];
#pragma unroll
    for (int o = 0; o < NB; ++o)
        xx[o] = *reinterpret_cast<const float4*>(m_out + ((ll)(b * NC + 48 + o)) * PPI + p0);
#pragma unroll
    for (int o = 0; o < NB; ++o) {
        float sc = scl_l[o], sh = shf_l[o];
        xx[o].x = fmaxf(0.f, fmaf(xx[o].x, sc, sh));
        xx[o].y = fmaxf(0.f, fmaf(xx[o].y, sc, sh));
        xx[o].z = fmaxf(0.f, fmaf(xx[o].z, sc, sh));
        xx[o].w = fmaxf(0.f, fmaf(xx[o].w, sc, sh));
    }

    // streaming branchless top-4 (strict > keeps jax lowest-index tie-break)
    float tv[4][4];
    int   ti[4][4];
#pragma unroll
    for (int j = 0; j < 4; ++j)
#pragma unroll
        for (int k = 0; k < 4; ++k) { tv[j][k] = -3.4e38f; ti[j][k] = 0; }

#pragma unroll 2
    for (int n = 0; n < NC; ++n) {
        const float* wr = weff_l[n];
        float4 v = make_float4(0.f, 0.f, 0.f, 0.f);
#pragma unroll
        for (int o = 0; o < NB; ++o) {
            float w = wr[o];
            v.x = fmaf(xx[o].x, w, v.x);
            v.y = fmaf(xx[o].y, w, v.y);
            v.z = fmaf(xx[o].z, w, v.z);
            v.w = fmaf(xx[o].w, w, v.w);
        }
        float vv[4] = {v.x, v.y, v.z, v.w};
#pragma unroll
        for (int j = 0; j < 4; ++j) {
            float x = vv[j];
            bool c0 = x > tv[j][0];
            bool c1 = x > tv[j][1];
            bool c2 = x > tv[j][2];
            bool c3 = x > tv[j][3];
            tv[j][3] = c2 ? tv[j][2] : fmaxf(x, tv[j][3]);
            ti[j][3] = c2 ? ti[j][2] : (c3 ? n : ti[j][3]);
            tv[j][2] = c1 ? tv[j][1] : fmaxf(x, tv[j][2]);
            ti[j][2] = c1 ? ti[j][1] : (c2 ? n : ti[j][2]);
            tv[j][1] = c0 ? tv[j][0] : fmaxf(x, tv[j][1]);
            ti[j][1] = c0 ? ti[j][0] : (c1 ? n : ti[j][1]);
            tv[j][0] = fmaxf(x, tv[j][0]);
            ti[j][0] = c0 ? n : ti[j][0];
        }
    }

    // softmax over kept 4 (tv sorted desc)
    float smx[4][4];
#pragma unroll
    for (int j = 0; j < 4; ++j) {
        float e1 = expf(tv[j][1] - tv[j][0]);
        float e2 = expf(tv[j][2] - tv[j][0]);
        float e3 = expf(tv[j][3] - tv[j][0]);
        float rz = 1.f / (1.f + e1 + e2 + e3);
        smx[j][0] = rz; smx[j][1] = e1 * rz; smx[j][2] = e2 * rz; smx[j][3] = e3 * rz;
    }

    // dense m write (overwrites the x stash at n=48..63 for this thread's pixels)
#define SEL(j, n) (((ti[j][0] == (n)) ? smx[j][0] : 0.f) + \
                   ((ti[j][1] == (n)) ? smx[j][1] : 0.f) + \
                   ((ti[j][2] == (n)) ? smx[j][2] : 0.f) + \
                   ((ti[j][3] == (n)) ? smx[j][3] : 0.f))
#pragma unroll 1
    for (int n = 0; n < NC; ++n) {
        float4 mv;
        mv.x = SEL(0, n); mv.y = SEL(1, n); mv.z = SEL(2, n); mv.w = SEL(3, n);
        *reinterpret_cast<float4*>(m_out + ((ll)(b * NC + n)) * PPI + p0) = mv;
    }
#undef SEL

    // per-pixel records (consumed by k3)
    ll gp = (ll)b * PPI + p0;
    uint4 pk;
    pk.x = (unsigned)ti[0][0] | ((unsigned)ti[0][1] << 8) | ((unsigned)ti[0][2] << 16) | ((unsigned)ti[0][3] << 24);
    pk.y = (unsigned)ti[1][0] | ((unsigned)ti[1][1] << 8) | ((unsigned)ti[1][2] << 16) | ((unsigned)ti[1][3] << 24);
    pk.z = (unsigned)ti[2][0] | ((unsigned)ti[2][1] << 8) | ((unsigned)ti[2][2] << 16) | ((unsigned)ti[2][3] << 24);
    pk.w = (unsigned)ti[3][0] | ((unsigned)ti[3][1] << 8) | ((unsigned)ti[3][2] << 16) | ((unsigned)ti[3][3] << 24);
    *reinterpret_cast<uint4*>(idx_out + gp) = pk;
#pragma unroll
    for (int k = 0; k < 4; ++k) {
        float4 sv = make_float4(smx[0][k], smx[1][k], smx[2][k], smx[3][k]);
        *reinterpret_cast<float4*>(sm_out + (ll)k * NPIX + gp) = sv;
    }

    // palette accumulation (per-wave LDS copies to cut contention)
    float4 i0 = *reinterpret_cast<const float4*>(img + ((ll)b * 3 + 0) * PPI + p0);
    float4 i1 = *reinterpret_cast<const float4*>(img + ((ll)b * 3 + 1) * PPI + p0);
    float4 i2 = *reinterpret_cast<const float4*>(img + ((ll)b * 3 + 2) * PPI + p0);
    float ir0[4] = {i0.x, i0.y, i0.z, i0.w};
    float ir1[4] = {i1.x, i1.y, i1.z, i1.w};
    float ir2[4] = {i2.x, i2.y, i2.z, i2.w};
#pragma unroll
    for (int j = 0; j < 4; ++j) {
#pragma unroll
        for (int k = 0; k < 4; ++k) {
            float s = smx[j][k];
            int   n = ti[j][k];
            atomicAdd(&den_loc[wave][n], s);
            atomicAdd(&num_loc[wave][0 * NC + n], s * ir0[j]);
            atomicAdd(&num_loc[wave][1 * NC + n], s * ir1[j]);
            atomicAdd(&num_loc[wave][2 * NC + n], s * ir2[j]);
        }
    }
    __syncthreads();
    if (tid < NC)
        atomicAdd(&den_g[b * NC + tid],
                  den_loc[0][tid] + den_loc[1][tid] + den_loc[2][tid] + den_loc[3][tid]);
    if (tid < 3 * NC)
        atomicAdd(&num_g[(ll)b * 3 * NC + tid],
                  num_loc[0][tid] + num_loc[1][tid] + num_loc[2][tid] + num_loc[3][tid]);
}

// ---------------------------------------------------------------------------
// k3: palette finalize (per-block in LDS) + write palette + reconstruction
// ---------------------------------------------------------------------------
__global__ __launch_bounds__(256) void k_recon(const unsigned* __restrict__ idx_in,
                                               const float* __restrict__ sm_in,
                                               const float* __restrict__ den_g,
                                               const float* __restrict__ num_g,
                                               float* __restrict__ pal_out,
                                               float* __restrict__ t_out)
{
    __shared__ float pal_l[3][NC];
    __shared__ float rden[NC];
    const int tid = threadIdx.x;
    const int b   = blockIdx.x >> 6;
    const int p0  = ((blockIdx.x & 63) << 10) + (tid << 2);

    if (tid < NC) rden[tid] = 1.f / (den_g[b * NC + tid] + 1e-8f);
    __syncthreads();
    if (tid < 3 * NC) {
        int c = tid >> 6, n = tid & 63;
        pal_l[c][n] = num_g[(ll)b * 3 * NC + tid] * rden[n];
    }
    __syncthreads();
    if ((blockIdx.x & 63) == 0 && tid < 3 * NC)
        pal_out[b * 3 * NC + tid] = pal_l[tid >> 6][tid & 63];

    ll gp = (ll)b * PPI + p0;
    uint4 pk  = *reinterpret_cast<const uint4*>(idx_in + gp);
    float4 s0 = *reinterpret_cast<const float4*>(sm_in + gp);
    float4 s1 = *reinterpret_cast<const float4*>(sm_in + (ll)NPIX + gp);
    float4 s2 = *reinterpret_cast<const float4*>(sm_in + 2ll * NPIX + gp);
    float4 s3 = *reinterpret_cast<const float4*>(sm_in + 3ll * NPIX + gp);
    unsigned pkv[4] = {pk.x, pk.y, pk.z, pk.w};
    float sA[4][4] = {{s0.x, s1.x, s2.x, s3.x}, {s0.y, s1.y, s2.y, s3.y},
                      {s0.z, s1.z, s2.z, s3.z}, {s0.w, s1.w, s2.w, s3.w}};

#pragma unroll
    for (int c = 0; c < 3; ++c) {
        float4 t;
        float* tp = &t.x;
#pragma unroll
        for (int j = 0; j < 4; ++j) {
            unsigned p = pkv[j];
            tp[j] = sA[j][0] * pal_l[c][p & 255] + sA[j][1] * pal_l[c][(p >> 8) & 255] +
                    sA[j][2] * pal_l[c][(p >> 16) & 255] + sA[j][3] * pal_l[c][p >> 24];
        }
        *reinterpret_cast<float4*>(t_out + ((ll)b * 3 + c) * PPI + p0) = t;
    }
}

// ---------------------------------------------------------------------------
extern "C" void kernel_launch(void* const* d_in, const int* in_sizes, int n_in,
                              void* d_out, int out_size, void* d_ws, size_t ws_size,
                              hipStream_t stream)
{
    const float* img   = (const float*)d_in[0];
    const float* feat  = (const float*)d_in[1];
    const float* wb    = (const float*)d_in[2];
    // d_in[3] = b_bneck: unused — bias cancels under BatchNorm mean-subtraction
    const float* gamma = (const float*)d_in[4];
    const float* beta  = (const float*)d_in[5];
    const float* wm    = (const float*)d_in[6];

    char* ws = (char*)d_ws;
    double*   gsum  = (double*)(ws + 0);      // 16 doubles
    double*   gsq   = (double*)(ws + 128);    // 16 doubles
    float*    den_g = (float*)(ws + 256);     // 8*64 floats
    float*    num_g = (float*)(ws + 2304);    // 8*3*64 floats  (end: 8448)
    unsigned* idx4  = (unsigned*)(ws + 8448);             // NPIX u32
    float*    smarr = (float*)(ws + 8448 + 4ll * NPIX);   // 4*NPIX f32

    float* t_out   = (float*)d_out;               // [8,3,256,256]
    float* m_out   = t_out + 3ll * NPIX;          // [8,64,256,256]
    float* pal_out = m_out + 64ll * NPIX;         // [8,3,64,1,1]

    hipMemsetAsync(ws, 0, 8448, stream);          // zero atomic accumulators

    k_conv <<<NPIX / 1024, 256, 0, stream>>>(feat, wb, gsum, gsq, m_out);
    k_mask <<<NPIX / 1024, 256, 0, stream>>>(img, gamma, beta, wm, gsum, gsq,
                                             den_g, num_g, m_out, idx4, smarr);
    k_recon<<<NPIX / 1024, 256, 0, stream>>>(idx4, smarr, den_g, num_g, pal_out, t_out);
}